// Round 3
// baseline (229.977 us; speedup 1.0000x reference)
//
#include <hip/hip_runtime.h>

// KAN layer forward, MI355X. Inputs AND outputs are float32 buffers.
// Outputs (flat concat, f32): y_out[1024,128], preacts[1024,128,128],
// postacts[1024,128,128], postspline[1024,128,128].
//
// R7 -> R8: ONE variable changed vs R7: all output stores are NONTEMPORAL.
// Theory: R5->R7 proved the kernel is insensitive to access pattern; the
// missing ~65us matches coef L2-thrash: 197MB of write-allocating streaming
// stores evict the 512KB coef working set from the 4MB/XCD L2s, so the
// 512MB of logical coef reads (256KB/block x 2048 blocks) miss to HBM
// (~78us at 6.6TB/s). nt stores bypass LRU -> coef stays L2-resident.
// Predicted: kernel ~100 -> ~50-60us, harness dur 220 -> ~165-180.
// If unchanged: thrash theory dead, kernel is at fill+overhead+write floor.

#define IN_DIM  128
#define OUT_DIM 128
#define NUMG    5
#define KORD    3
#define NB      8          // NUMG + KORD basis functions
#define SIZE    (IN_DIM * OUT_DIM)
#define BATCH   1024

typedef float v4f __attribute__((ext_vector_type(4)));

__global__ __launch_bounds__(256) void kan_fused(
    const float* __restrict__ x,
    const float* __restrict__ grid,
    const float* __restrict__ coef,
    const float* __restrict__ scale_base,
    const float* __restrict__ scale_sp,
    const float* __restrict__ mask,
    float* __restrict__ out)
{
    __shared__ float sB[IN_DIM][NB];        // [i][m]
    __shared__ float sSilu[IN_DIM];
    __shared__ float sXv[IN_DIM];
    __shared__ float sPart[4][2][2][IN_DIM]; // [wave][j-of-pair][m-half][i]

    const int tid  = threadIdx.x;
    const int b    = blockIdx.x >> 1;          // batch row
    const int half = blockIdx.x & 1;           // j half: [0,64) or [64,128)

    // ---- Phase 1: basis + silu for i = tid (threads 0..127) ----
    if (tid < IN_DIM) {
        const int i = tid;
        const float xv = x[b * IN_DIM + i];

        float gr[NUMG + 1];
        #pragma unroll
        for (int r = 0; r <= NUMG; ++r) gr[r] = grid[i * (NUMG + 1) + r];

        const float h = (gr[NUMG] - gr[0]) * (1.0f / NUMG);
        float t[NUMG + 1 + 2 * KORD];             // 12 knots
        t[2] = gr[0] - h; t[1] = t[2] - h; t[0] = t[1] - h;
        #pragma unroll
        for (int r = 0; r <= NUMG; ++r) t[KORD + r] = gr[r];
        t[9] = gr[NUMG] + h; t[10] = t[9] + h; t[11] = t[10] + h;

        float B[NUMG + 2 * KORD];                 // 11 -> 10 -> 9 -> 8
        #pragma unroll
        for (int m = 0; m < NUMG + 2 * KORD; ++m)
            B[m] = (xv >= t[m] && xv < t[m + 1]) ? 1.0f : 0.0f;
        #pragma unroll
        for (int p = 1; p <= KORD; ++p) {
            #pragma unroll
            for (int m = 0; m < NUMG + 2 * KORD - p; ++m) {
                B[m] = (xv - t[m]) / (t[m + p] - t[m]) * B[m]
                     + (t[m + p + 1] - xv) / (t[m + p + 1] - t[m + 1]) * B[m + 1];
            }
        }

        *(float4*)&sB[i][0] = make_float4(B[0], B[1], B[2], B[3]);
        *(float4*)&sB[i][4] = make_float4(B[4], B[5], B[6], B[7]);
        sSilu[i] = xv / (1.0f + __expf(-xv));
        sXv[i]   = xv;
    }
    __syncthreads();

    const int lane = tid & 63;
    const int w    = tid >> 6;
    const int a    = lane >> 1;                // i sub-index for loads
    const int mh   = lane & 1;                 // which m-half this lane dots
    const int il   = lane & 31;                // i-quad index for stores
    const int jh   = lane >> 5;                // which j of the pair (stores)
    const int i4   = il << 2;

    // Basis fragments: j-independent, load once. basq[q] pairs with the
    // coef float4 this lane loads at slot q (i = 32q + a, m-half = mh).
    float4 basq[4];
    #pragma unroll
    for (int q = 0; q < 4; ++q)
        basq[q] = *(const float4*)&sB[32 * q + a][4 * mh];

    const float4 slv = *(const float4*)&sSilu[i4];
    const float4 pxv = *(const float4*)&sXv[i4];
    const float slA[4] = {slv.x, slv.y, slv.z, slv.w};
    const v4f  pxn = {pxv.x, pxv.y, pxv.z, pxv.w};

    float* out_y   = out;
    float* out_pre = out + BATCH * OUT_DIM;
    float* out_act = out_pre + (size_t)BATCH * SIZE;
    float* out_spl = out_act + (size_t)BATCH * SIZE;

    const int jbase = half * 64 + w * 16;      // wave owns 16 j, 2 per iter
    const float4* cp = (const float4*)coef;

    #pragma unroll 2
    for (int jj = 0; jj < 8; ++jj) {
        const int j0 = jbase + 2 * jj;

        // 8 coef loads, each 1KB fully contiguous (16 lines, 100% covered)
        float4 cf[2][4];
        #pragma unroll
        for (int jp = 0; jp < 2; ++jp)
            #pragma unroll
            for (int q = 0; q < 4; ++q)
                cf[jp][q] = cp[(size_t)(j0 + jp) * 256 + 64 * q + lane];

        // partial dots -> per-wave LDS bounce (no barrier: within-wave)
        #pragma unroll
        for (int jp = 0; jp < 2; ++jp) {
            #pragma unroll
            for (int q = 0; q < 4; ++q) {
                const float4 c = cf[jp][q];
                const float4 bq = basq[q];
                float r =        c.x * bq.x;
                r = fmaf(c.y, bq.y, r);
                r = fmaf(c.z, bq.z, r);
                r = fmaf(c.w, bq.w, r);
                sPart[w][jp][mh][32 * q + a] = r;
            }
        }

        // re-mapped read-back: lane owns (i-quad i4, j = j0+jh)
        const float4 spE = *(const float4*)&sPart[w][jh][0][i4];
        const float4 spO = *(const float4*)&sPart[w][jh][1][i4];
        const float spA[4] = {spE.x + spO.x, spE.y + spO.y,
                              spE.z + spO.z, spE.w + spO.w};

        const int sS = (j0 + jh) * IN_DIM + i4;
        const float4 mkv = *(const float4*)&mask[sS];
        const float4 sbv = *(const float4*)&scale_base[sS];
        const float4 ssv = *(const float4*)&scale_sp[sS];
        const float mkA[4] = {mkv.x, mkv.y, mkv.z, mkv.w};
        const float sbA[4] = {sbv.x, sbv.y, sbv.z, sbv.w};
        const float ssA[4] = {ssv.x, ssv.y, ssv.z, ssv.w};

        float y[4];
        #pragma unroll
        for (int k = 0; k < 4; ++k)
            y[k] = mkA[k] * (sbA[k] * slA[k] + ssA[k] * spA[k]);

        const size_t e = (size_t)b * SIZE + (size_t)sS;
        const v4f yv  = {y[0], y[1], y[2], y[3]};
        const v4f sv  = {spA[0], spA[1], spA[2], spA[3]};
        __builtin_nontemporal_store(pxn, (v4f*)&out_pre[e]);   // x broadcast
        __builtin_nontemporal_store(yv,  (v4f*)&out_act[e]);
        __builtin_nontemporal_store(sv,  (v4f*)&out_spl[e]);

        // y_out[b][j0+jh] = sum over i: width-32 half-wave reduction
        float acc = (y[0] + y[1]) + (y[2] + y[3]);
        #pragma unroll
        for (int off = 16; off > 0; off >>= 1)
            acc += __shfl_down(acc, off, 32);
        if (il == 0)
            __builtin_nontemporal_store(acc, &out_y[b * OUT_DIM + j0 + jh]);
    }
}

extern "C" void kernel_launch(void* const* d_in, const int* in_sizes, int n_in,
                              void* d_out, int out_size, void* d_ws, size_t ws_size,
                              hipStream_t stream)
{
    hipLaunchKernelGGL(kan_fused, dim3(BATCH * 2), dim3(256), 0, stream,
                       (const float*)d_in[0], (const float*)d_in[1],
                       (const float*)d_in[2], (const float*)d_in[3],
                       (const float*)d_in[4], (const float*)d_in[5],
                       (float*)d_out);
}

// Round 4
// 227.294 us; speedup vs baseline: 1.0118x; 1.0118x over previous
//
#include <hip/hip_runtime.h>

// KAN layer forward, MI355X. Inputs AND outputs are float32 buffers.
// Outputs (flat concat, f32): y_out[1024,128], preacts[1024,128,128],
// postacts[1024,128,128], postspline[1024,128,128].
//
// R8 -> R9: R5-R8 proved the kernel (~100us) is invariant to access pattern
// and store cache policy. Only total-HBM-volume fits all rounds:
// 202MB writes + 512MB logical coef reads (L2 recycled ~6x by the store
// stream -> every block's 256KB coef read is cold) ~= 714MB @6.6TB/s ~=
// 108us. Fix the VOLUME: batch-group blocks. Block = (8 j) x (8 batch
// rows), grid still 2048. Each wave holds its j-pair's coef slice in 8
// float4 REGISTERS (loaded once, 1KB-contiguous instrs) + scales/mask in
// regs, and loops over the 8 rows. Coef logical HBM: 512MB -> 64MB.
// Inner body identical to R7's verified pipeline (basq LDS reads are the
// linear 16B*lane conflict-free pattern; per-wave sPart bounce, no barrier).
// Predicted: kernel -> ~55-65us, dur_us 220 -> ~175-190.

#define IN_DIM  128
#define OUT_DIM 128
#define NUMG    5
#define KORD    3
#define NB      8          // NUMG + KORD basis functions
#define SIZE    (IN_DIM * OUT_DIM)
#define BATCH   1024
#define G       8          // batch rows per block
#define JB      8          // j per block
#define NBG     (BATCH / G)    // 128 batch groups
#define NJO     (OUT_DIM / JB) // 16 j groups

__global__ __launch_bounds__(256) void kan_fused(
    const float* __restrict__ x,
    const float* __restrict__ grid,
    const float* __restrict__ coef,
    const float* __restrict__ scale_base,
    const float* __restrict__ scale_sp,
    const float* __restrict__ mask,
    float* __restrict__ out)
{
    __shared__ float sB[G][IN_DIM][NB];       // 32 KB  [row][i][m]
    __shared__ float sSilu[G][IN_DIM];        // 4 KB
    __shared__ float sXv[G][IN_DIM];          // 4 KB
    __shared__ float sPart[4][2][2][IN_DIM];  // 8 KB [wave][jp][m-half][i]

    const int tid = threadIdx.x;
    const int bg  = blockIdx.x & (NBG - 1);   // batch group (low bits:
    const int jo  = blockIdx.x >> 7;          //  consecutive blocks share coef)

    // ---- Phase 1: basis + silu for G rows x 128 i (all 256 threads) ----
    #pragma unroll
    for (int it = 0; it < (G * IN_DIM) / 256; ++it) {
        const int idx = it * 256 + tid;
        const int r   = idx >> 7;
        const int i   = idx & 127;
        const float xv = x[(bg * G + r) * IN_DIM + i];

        float gr[NUMG + 1];
        #pragma unroll
        for (int rr = 0; rr <= NUMG; ++rr) gr[rr] = grid[i * (NUMG + 1) + rr];

        const float h = (gr[NUMG] - gr[0]) * (1.0f / NUMG);
        float t[NUMG + 1 + 2 * KORD];             // 12 knots
        t[2] = gr[0] - h; t[1] = t[2] - h; t[0] = t[1] - h;
        #pragma unroll
        for (int rr = 0; rr <= NUMG; ++rr) t[KORD + rr] = gr[rr];
        t[9] = gr[NUMG] + h; t[10] = t[9] + h; t[11] = t[10] + h;

        float B[NUMG + 2 * KORD];                 // 11 -> 10 -> 9 -> 8
        #pragma unroll
        for (int m = 0; m < NUMG + 2 * KORD; ++m)
            B[m] = (xv >= t[m] && xv < t[m + 1]) ? 1.0f : 0.0f;
        #pragma unroll
        for (int p = 1; p <= KORD; ++p) {
            #pragma unroll
            for (int m = 0; m < NUMG + 2 * KORD - p; ++m) {
                B[m] = (xv - t[m]) / (t[m + p] - t[m]) * B[m]
                     + (t[m + p + 1] - xv) / (t[m + p + 1] - t[m + 1]) * B[m + 1];
            }
        }

        *(float4*)&sB[r][i][0] = make_float4(B[0], B[1], B[2], B[3]);
        *(float4*)&sB[r][i][4] = make_float4(B[4], B[5], B[6], B[7]);
        sSilu[r][i] = xv / (1.0f + __expf(-xv));
        sXv[r][i]   = xv;
    }
    __syncthreads();

    // ---- Phase 2: wave w owns j-pair (j0, j0+1); loop over G rows ----
    const int lane = tid & 63;
    const int w    = tid >> 6;
    const int a    = lane >> 1;                // i sub-index for dots
    const int mh   = lane & 1;                 // m-half this lane dots
    const int il   = lane & 31;                // i-quad index for stores
    const int jh   = lane >> 5;                // which j of the pair (stores)
    const int i4   = il << 2;

    const int j0 = jo * JB + w * 2;
    const float4* cp = (const float4*)coef;

    // Coef slice for this wave's 2 j: 8 x 1KB fully-contiguous loads,
    // held in registers across all G rows (immune to L2 turnover).
    float4 cfR[2][4];
    #pragma unroll
    for (int jp = 0; jp < 2; ++jp)
        #pragma unroll
        for (int q = 0; q < 4; ++q)
            cfR[jp][q] = cp[(size_t)(j0 + jp) * 256 + 64 * q + lane];

    // Scales/mask for this lane's store slot (i-quad i4, j = j0+jh):
    // j-dependent only -> load once.
    const int sS = (j0 + jh) * IN_DIM + i4;
    const float4 mkv = *(const float4*)&mask[sS];
    const float4 sbv = *(const float4*)&scale_base[sS];
    const float4 ssv = *(const float4*)&scale_sp[sS];
    const float mkA[4] = {mkv.x, mkv.y, mkv.z, mkv.w};
    const float sbA[4] = {sbv.x, sbv.y, sbv.z, sbv.w};
    const float ssA[4] = {ssv.x, ssv.y, ssv.z, ssv.w};

    float* out_y   = out;
    float* out_pre = out + BATCH * OUT_DIM;
    float* out_act = out_pre + (size_t)BATCH * SIZE;
    float* out_spl = out_act + (size_t)BATCH * SIZE;

    #pragma unroll 2
    for (int r = 0; r < G; ++r) {
        // basis fragments for row r (linear 16B*lane pattern, conflict-free)
        float4 basq[4];
        #pragma unroll
        for (int q = 0; q < 4; ++q)
            basq[q] = *(const float4*)&sB[r][32 * q + a][4 * mh];

        // partial dots -> per-wave LDS bounce (no barrier: within-wave)
        #pragma unroll
        for (int jp = 0; jp < 2; ++jp) {
            #pragma unroll
            for (int q = 0; q < 4; ++q) {
                const float4 c  = cfR[jp][q];
                const float4 bq = basq[q];
                float rr =       c.x * bq.x;
                rr = fmaf(c.y, bq.y, rr);
                rr = fmaf(c.z, bq.z, rr);
                rr = fmaf(c.w, bq.w, rr);
                sPart[w][jp][mh][32 * q + a] = rr;
            }
        }

        // re-mapped read-back: lane owns (i-quad i4, j = j0+jh)
        const float4 spE = *(const float4*)&sPart[w][jh][0][i4];
        const float4 spO = *(const float4*)&sPart[w][jh][1][i4];
        const float spA[4] = {spE.x + spO.x, spE.y + spO.y,
                              spE.z + spO.z, spE.w + spO.w};

        const float4 slv = *(const float4*)&sSilu[r][i4];
        const float4 pxv = *(const float4*)&sXv[r][i4];
        const float slA[4] = {slv.x, slv.y, slv.z, slv.w};

        float y[4];
        #pragma unroll
        for (int k = 0; k < 4; ++k)
            y[k] = mkA[k] * (sbA[k] * slA[k] + ssA[k] * spA[k]);

        const int b_r = bg * G + r;
        const size_t e = (size_t)b_r * SIZE + (size_t)sS;
        *(float4*)&out_pre[e] = pxv;                            // x broadcast
        *(float4*)&out_act[e] = make_float4(y[0], y[1], y[2], y[3]);
        *(float4*)&out_spl[e] = make_float4(spA[0], spA[1], spA[2], spA[3]);

        // y_out[b_r][j0+jh] = sum over i: width-32 half-wave reduction
        float acc = (y[0] + y[1]) + (y[2] + y[3]);
        #pragma unroll
        for (int off = 16; off > 0; off >>= 1)
            acc += __shfl_down(acc, off, 32);
        if (il == 0) out_y[b_r * OUT_DIM + j0 + jh] = acc;
    }
}

extern "C" void kernel_launch(void* const* d_in, const int* in_sizes, int n_in,
                              void* d_out, int out_size, void* d_ws, size_t ws_size,
                              hipStream_t stream)
{
    hipLaunchKernelGGL(kan_fused, dim3(NJO * NBG), dim3(256), 0, stream,
                       (const float*)d_in[0], (const float*)d_in[1],
                       (const float*)d_in[2], (const float*)d_in[3],
                       (const float*)d_in[4], (const float*)d_in[5],
                       (float*)d_out);
}

// Round 5
// 212.196 us; speedup vs baseline: 1.0838x; 1.0712x over previous
//
#include <hip/hip_runtime.h>

// KAN layer forward, MI355X. Inputs AND outputs are float32 buffers.
// Outputs (flat concat, f32): y_out[1024,128], preacts[1024,128,128],
// postacts[1024,128,128], postspline[1024,128,128].
//
// R9 -> R10: pattern (R7), cache policy (R8) and volume (R9) all neutral ->
// kernel is DS-LATENCY-CHAIN bound: every round kept serial LDS round-trips
// in the inner loop (sPart write->wait->read bounce + 5 serial shuffles per
// row ~= 850-1000 cyc un-hideable chain x8 rows). This version removes all
// per-row DS chains:
//  - basis stored TRANSPOSED sBT[r][m][i]; lane (i-quad il, j jh) reads its
//    fragment directly as 8x ds_read_b128 (16B lane stride); coef for its
//    own (i-quad,j) lives in 32 REGISTERS (loaded once/block, reused 8 rows)
//    -> dot is pure register FMA, no bounce, only independent DS reads.
//  - y_out: per-lane partials py[0..7] in regs, ONE batched 5-step butterfly
//    after the row loop (chain 5 latencies total, was 5x8).
//  - phase 1: thread's 4 rows share i -> same knots -> 30 reciprocals
//    computed once, recurrence is mul/fma only (216 -> 30 divides/thread).
//  - LDS 40KB -> 4 blocks/CU (16 waves/CU, was 12).
// Predict: kernel ~100 -> ~45-60us, dur 227 -> ~160-185. If unchanged:
// residual is harness-fixed (fill+overhead) -> ceiling write-up next round.

#define IN_DIM  128
#define OUT_DIM 128
#define NUMG    5
#define KORD    3
#define NB      8          // NUMG + KORD basis functions
#define SIZE    (IN_DIM * OUT_DIM)
#define BATCH   1024
#define G       8          // batch rows per block
#define JB      8          // j per block
#define NBG     (BATCH / G)    // 128 batch groups
#define NJO     (OUT_DIM / JB) // 16 j groups

__global__ __launch_bounds__(256) void kan_fused(
    const float* __restrict__ x,
    const float* __restrict__ grid,
    const float* __restrict__ coef,
    const float* __restrict__ scale_base,
    const float* __restrict__ scale_sp,
    const float* __restrict__ mask,
    float* __restrict__ out)
{
    __shared__ float sBT[G][NB][IN_DIM];      // 32 KB [row][m][i] transposed
    __shared__ float sSilu[G][IN_DIM];        // 4 KB
    __shared__ float sXv[G][IN_DIM];          // 4 KB

    const int tid = threadIdx.x;
    const int bg  = blockIdx.x & (NBG - 1);   // batch group (low bits share
    const int jo  = blockIdx.x >> 7;          //  coef across nearby blocks)

    // ---- Phase 1: basis + silu, 4 rows per thread, all same i ----
    {
        const int i  = tid & 127;
        const int r0 = tid >> 7;              // 0 or 1

        float gr[NUMG + 1];
        #pragma unroll
        for (int rr = 0; rr <= NUMG; ++rr) gr[rr] = grid[i * (NUMG + 1) + rr];

        const float h = (gr[NUMG] - gr[0]) * (1.0f / NUMG);
        float t[NUMG + 1 + 2 * KORD];             // 12 knots
        t[2] = gr[0] - h; t[1] = t[2] - h; t[0] = t[1] - h;
        #pragma unroll
        for (int rr = 0; rr <= NUMG; ++rr) t[KORD + rr] = gr[rr];
        t[9] = gr[NUMG] + h; t[10] = t[9] + h; t[11] = t[10] + h;

        // knot-difference reciprocals (shared by all 4 rows of this thread)
        float rcp1[11], rcp2[10], rcp3[9];
        #pragma unroll
        for (int m = 0; m < 11; ++m) rcp1[m] = 1.0f / (t[m + 1] - t[m]);
        #pragma unroll
        for (int m = 0; m < 10; ++m) rcp2[m] = 1.0f / (t[m + 2] - t[m]);
        #pragma unroll
        for (int m = 0; m < 9;  ++m) rcp3[m] = 1.0f / (t[m + 3] - t[m]);

        #pragma unroll
        for (int it = 0; it < 4; ++it) {
            const int r = it * 2 + r0;
            const float xv = x[(bg * G + r) * IN_DIM + i];

            float B[NUMG + 2 * KORD];             // 11 -> 10 -> 9 -> 8
            #pragma unroll
            for (int m = 0; m < NUMG + 2 * KORD; ++m)
                B[m] = (xv >= t[m] && xv < t[m + 1]) ? 1.0f : 0.0f;
            #pragma unroll
            for (int m = 0; m < 10; ++m)
                B[m] = (xv - t[m]) * rcp1[m] * B[m]
                     + (t[m + 2] - xv) * rcp1[m + 1] * B[m + 1];
            #pragma unroll
            for (int m = 0; m < 9; ++m)
                B[m] = (xv - t[m]) * rcp2[m] * B[m]
                     + (t[m + 3] - xv) * rcp2[m + 1] * B[m + 1];
            #pragma unroll
            for (int m = 0; m < 8; ++m)
                B[m] = (xv - t[m]) * rcp3[m] * B[m]
                     + (t[m + 4] - xv) * rcp3[m + 1] * B[m + 1];

            #pragma unroll
            for (int m = 0; m < NB; ++m) sBT[r][m][i] = B[m];
            sSilu[r][i] = xv / (1.0f + __expf(-xv));
            sXv[r][i]   = xv;
        }
    }
    __syncthreads();

    // ---- Phase 2: wave w owns j-pair; lane owns (i-quad, one j) ----
    const int lane = tid & 63;
    const int w    = tid >> 6;
    const int il   = lane & 31;                // i-quad index
    const int jh   = lane >> 5;                // which j of the wave's pair
    const int i4   = il << 2;
    const int j    = jo * JB + w * 2 + jh;

    // Coef for THIS lane's 4 i at THIS j: 8 float4 = 32 regs, loaded once.
    // cfs[k][m] = coef[j][i4+k][m]
    float cfs[4][NB];
    {
        const float4* cp = (const float4*)coef;
        #pragma unroll
        for (int k = 0; k < 4; ++k) {
            const float4 lo = cp[(size_t)j * 256 + il * 8 + 2 * k];
            const float4 hi = cp[(size_t)j * 256 + il * 8 + 2 * k + 1];
            cfs[k][0] = lo.x; cfs[k][1] = lo.y; cfs[k][2] = lo.z; cfs[k][3] = lo.w;
            cfs[k][4] = hi.x; cfs[k][5] = hi.y; cfs[k][6] = hi.z; cfs[k][7] = hi.w;
        }
    }

    const int sS = j * IN_DIM + i4;
    const float4 mkv = *(const float4*)&mask[sS];
    const float4 sbv = *(const float4*)&scale_base[sS];
    const float4 ssv = *(const float4*)&scale_sp[sS];
    const float mkA[4] = {mkv.x, mkv.y, mkv.z, mkv.w};
    const float sbA[4] = {sbv.x, sbv.y, sbv.z, sbv.w};
    const float ssA[4] = {ssv.x, ssv.y, ssv.z, ssv.w};

    float* out_y   = out;
    float* out_pre = out + BATCH * OUT_DIM;
    float* out_act = out_pre + (size_t)BATCH * SIZE;
    float* out_spl = out_act + (size_t)BATCH * SIZE;

    float py[G];                               // per-lane y_out partials

    #pragma unroll 2
    for (int r = 0; r < G; ++r) {
        // 8 independent b128 reads: basis[m] for this lane's 4 i
        float4 bas[NB];
        #pragma unroll
        for (int m = 0; m < NB; ++m)
            bas[m] = *(const float4*)&sBT[r][m][i4];

        float sp0 = cfs[0][0] * bas[0].x;
        float sp1 = cfs[1][0] * bas[0].y;
        float sp2 = cfs[2][0] * bas[0].z;
        float sp3 = cfs[3][0] * bas[0].w;
        #pragma unroll
        for (int m = 1; m < NB; ++m) {
            const float4 b4 = bas[m];
            sp0 = fmaf(cfs[0][m], b4.x, sp0);
            sp1 = fmaf(cfs[1][m], b4.y, sp1);
            sp2 = fmaf(cfs[2][m], b4.z, sp2);
            sp3 = fmaf(cfs[3][m], b4.w, sp3);
        }

        const float4 slv = *(const float4*)&sSilu[r][i4];
        const float4 pxv = *(const float4*)&sXv[r][i4];
        const float spA[4] = {sp0, sp1, sp2, sp3};
        const float slA[4] = {slv.x, slv.y, slv.z, slv.w};

        float y[4];
        #pragma unroll
        for (int k = 0; k < 4; ++k)
            y[k] = mkA[k] * (sbA[k] * slA[k] + ssA[k] * spA[k]);

        const int b_r = bg * G + r;
        const size_t e = (size_t)b_r * SIZE + (size_t)sS;
        *(float4*)&out_pre[e] = pxv;                            // x broadcast
        *(float4*)&out_act[e] = make_float4(y[0], y[1], y[2], y[3]);
        *(float4*)&out_spl[e] = make_float4(spA[0], spA[1], spA[2], spA[3]);

        py[r] = (y[0] + y[1]) + (y[2] + y[3]);
    }

    // ---- Batched y_out reduction: one butterfly for all 8 rows ----
    #pragma unroll
    for (int off = 16; off > 0; off >>= 1) {
        #pragma unroll
        for (int r = 0; r < G; ++r)
            py[r] += __shfl_down(py[r], off, 32);
    }
    if (il == 0) {
        #pragma unroll
        for (int r = 0; r < G; ++r)
            out_y[(bg * G + r) * OUT_DIM + j] = py[r];
    }
}

extern "C" void kernel_launch(void* const* d_in, const int* in_sizes, int n_in,
                              void* d_out, int out_size, void* d_ws, size_t ws_size,
                              hipStream_t stream)
{
    hipLaunchKernelGGL(kan_fused, dim3(NJO * NBG), dim3(256), 0, stream,
                       (const float*)d_in[0], (const float*)d_in[1],
                       (const float*)d_in[2], (const float*)d_in[3],
                       (const float*)d_in[4], (const float*)d_in[5],
                       (float*)d_out);
}